// Round 1
// 321.553 us; speedup vs baseline: 1.0904x; 1.0904x over previous
//
#include <hip/hip_runtime.h>
#include <hip/hip_fp8.h>
#include <hip/hip_fp16.h>

// Problem constants: N=50000, E=1.6M, dims 512 -> 128 -> 64
#define IN_DIM  512
#define HID_DIM 128
#define OUT_DIM 64

typedef unsigned short ushort_t;
typedef ushort_t ushort8 __attribute__((ext_vector_type(8)));
typedef __bf16  bf16x8  __attribute__((ext_vector_type(8)));
typedef float   floatx4 __attribute__((ext_vector_type(4)));

// fp32 -> bf16 round-to-nearest-even (bit trick; inputs are finite)
__device__ __forceinline__ ushort_t f2bf(float f) {
    union { float f; unsigned u; } v; v.f = f;
    unsigned r = v.u + 0x7FFFu + ((v.u >> 16) & 1u);
    return (ushort_t)(r >> 16);
}
__device__ __forceinline__ float bf2f(ushort_t u) {
    return __uint_as_float(((unsigned)u) << 16);
}
// fp32 <-> fp8 e4m3 (OCP fn) via HIP type (HW v_cvt on gfx950)
__device__ __forceinline__ unsigned char f2fp8(float f) {
    __hip_fp8_e4m3 t(f); return (unsigned char)t.__x;
}
__device__ __forceinline__ float fp82f(unsigned char b) {
    __hip_fp8_e4m3 t; t.__x = (__hip_fp8_storage_t)b; return (float)t;
}

__global__ void k_zero(int* __restrict__ p, int n) {
    int i = blockIdx.x * blockDim.x + threadIdx.x;
    if (i < n) p[i] = 0;
}

// ---------------------------------------------------------------------------
// CSR build, bucket-level (128 rows/bucket):
//   bhist (LDS-privatized bucket histogram) -> bscan -> bin -> unbin
// Requires n <= 65536 (col fits 16 bits, nbk <= 512 fits 9 bits).
// Final edge record is 4 bytes: {col:16 | fp16 weight:16}.  Row segments are
// padded to a multiple of 8 records (w=0 dummies) and start 8-record-aligned
// so SpMM can use aligned dwordx4 loads with zero tail handling.
// ---------------------------------------------------------------------------

#define BIN_TILE 4096
#define BH_TILE  8192
#define NBMAX    512
// per-bucket slack for per-row pad-to-8 (<=128*7=896) + base 8-alignment
#define BSLACK   1032

__global__ __launch_bounds__(256) void k_bhist(const int* __restrict__ rows,
                                               int* __restrict__ bcnt, int E) {
    __shared__ int lc[NBMAX];
    const int t = threadIdx.x;
    lc[t] = 0; lc[t + 256] = 0;
    __syncthreads();
    const int base = blockIdx.x * BH_TILE;
#pragma unroll
    for (int j = 0; j < BH_TILE / 256; ++j) {
        int e = base + t + j * 256;
        if (e < E) atomicAdd(&lc[rows[e] >> 7], 1);
    }
    __syncthreads();
    if (lc[t])       atomicAdd(&bcnt[t], lc[t]);
    if (lc[t + 256]) atomicAdd(&bcnt[t + 256], lc[t + 256]);
}

// bucket_base = exclusive prefix over (round8(bcnt)+1024): every base is
// 8-aligned with enough slack for row padding.
__global__ __launch_bounds__(256) void k_bscan(const int* __restrict__ bcnt,
                                               int* __restrict__ bucket_base,
                                               int* __restrict__ bucket_fill,
                                               int nbk) {
    __shared__ int s[NBMAX];
    const int t = threadIdx.x;
    s[t]       = (t < nbk)       ? (((bcnt[t] + 7) & ~7) + 1024)       : 0;
    s[t + 256] = (t + 256 < nbk) ? (((bcnt[t + 256] + 7) & ~7) + 1024) : 0;
    __syncthreads();
    for (int d = 1; d < NBMAX; d <<= 1) {
        int v0 = (t >= d) ? s[t - d] : 0;
        int v1 = (t + 256 >= d) ? s[t + 256 - d] : 0;
        __syncthreads();
        s[t] += v0; s[t + 256] += v1;
        __syncthreads();
    }
#pragma unroll
    for (int l = 0; l < 2; ++l) {
        int i = t + l * 256;
        if (i < nbk) {
            int v = (i == 0) ? 0 : s[i - 1];
            bucket_base[i] = v;
            bucket_fill[i] = v;
        }
    }
}

// Phase A: bin edges into bucket regions of ept with LDS staging.
// Record: .x = col | rowoff<<16 | bucket<<23, .y = fp16(weight) << 16.
__global__ __launch_bounds__(256) void k_bin(const int* __restrict__ rows,
                                             const int* __restrict__ cols,
                                             const float* __restrict__ ew,
                                             int* __restrict__ bucket_fill,
                                             int2* __restrict__ ept, int E, int nbk) {
    __shared__ int cnt[NBMAX], inc[NBMAX], cnt2[NBMAX], gbase[NBMAX];
    __shared__ int2 stage[BIN_TILE];
    const int t = threadIdx.x;
    const int tile0 = blockIdx.x * BIN_TILE;

    cnt[t] = 0; cnt[t + 256] = 0; cnt2[t] = 0; cnt2[t + 256] = 0;
    __syncthreads();

    int px[16], pw[16];
    int nv = 0;
#pragma unroll
    for (int j = 0; j < 16; ++j) {
        int e = tile0 + t + j * 256;
        if (e < E) {
            int r = rows[e];
            int b = r >> 7;
            px[nv] = cols[e] | ((r & 127) << 16) | (b << 23);
            pw[nv] = ((int)__half_as_ushort(__float2half(ew[e]))) << 16;
            ++nv;
            atomicAdd(&cnt[b], 1);
        }
    }
    __syncthreads();

    inc[t] = cnt[t]; inc[t + 256] = cnt[t + 256];
    __syncthreads();
    for (int d = 1; d < NBMAX; d <<= 1) {
        int v0 = (t >= d) ? inc[t - d] : 0;
        int v1 = (t + 256 >= d) ? inc[t + 256 - d] : 0;
        __syncthreads();
        inc[t] += v0; inc[t + 256] += v1;
        __syncthreads();
    }

    if (t < nbk && cnt[t] > 0)             gbase[t]       = atomicAdd(&bucket_fill[t], cnt[t]);
    if (t + 256 < nbk && cnt[t + 256] > 0) gbase[t + 256] = atomicAdd(&bucket_fill[t + 256], cnt[t + 256]);

    for (int j = 0; j < nv; ++j) {
        int b = ((unsigned)px[j]) >> 23;
        int off = (b == 0) ? 0 : inc[b - 1];
        int r = atomicAdd(&cnt2[b], 1);
        stage[off + r] = make_int2(px[j], pw[j]);
    }
    __syncthreads();

    int total = inc[nbk - 1];
    for (int s = t; s < total; s += 256) {
        int2 rec = stage[s];
        int b = ((unsigned)rec.x) >> 23;
        int off = (b == 0) ? 0 : inc[b - 1];
        ept[gbase[b] + (s - off)] = rec;
    }
}

// Phase B: one block per bucket; derives padded per-row segments rseg[r] =
// {start, start+round8(deg)} and scatters 4-byte records; pads with w=0.
__global__ __launch_bounds__(256) void k_unbin(const int* __restrict__ bucket_base,
                                               const int* __restrict__ bcnt,
                                               const int2* __restrict__ ept,
                                               unsigned* __restrict__ ep4,
                                               int2* __restrict__ rseg,
                                               int n) {
    __shared__ int rcnt[128], sc[128], fill[128], rbase[128];
    const int b = blockIdx.x;
    const int t = threadIdx.x;
    const int r0 = b << 7;
    const int nrows = (n - r0 < 128) ? (n - r0) : 128;
    const int bstart = bucket_base[b];
    const int bend   = bstart + bcnt[b];

    if (t < 128) rcnt[t] = 0;
    __syncthreads();

    for (int e = bstart + t; e < bend; e += 256) {
        int ro = (ept[e].x >> 16) & 127;
        atomicAdd(&rcnt[ro], 1);
    }
    __syncthreads();

    if (t < 128) sc[t] = (rcnt[t] + 7) & ~7;   // padded per-row counts
    __syncthreads();
    for (int d = 1; d < 128; d <<= 1) {
        int v = (t >= d && t < 128) ? sc[t - d] : 0;
        __syncthreads();
        if (t < 128) sc[t] += v;
        __syncthreads();
    }
    if (t < 128) {
        int start = bstart + ((t == 0) ? 0 : sc[t - 1]);
        rbase[t] = start;
        fill[t]  = start;
        if (t < nrows)
            rseg[r0 + t] = make_int2(start, start + ((rcnt[t] + 7) & ~7));
    }
    __syncthreads();

    for (int e = bstart + t; e < bend; e += 256) {
        int2 rec = ept[e];
        int ro = (rec.x >> 16) & 127;
        int p = atomicAdd(&fill[ro], 1);
        ep4[p] = ((unsigned)rec.x & 0xFFFFu) | ((unsigned)rec.y & 0xFFFF0000u);
    }
    __syncthreads();

    if (t < 128) {
        int pend = rbase[t] + ((rcnt[t] + 7) & ~7);
        for (int p = fill[t]; p < pend; ++p) ep4[p] = 0u;  // col 0, w = 0
    }
}

// --- fallback CSR build for n > 65536: hist -> 3-kernel scan -> scatter ----

__global__ void k_hist(const int* __restrict__ rows, int* __restrict__ deg, int E) {
    int i = blockIdx.x * blockDim.x + threadIdx.x;
    if (i < E) atomicAdd(&deg[rows[i]], 1);
}

#define SCAN_TILE 2048

__global__ __launch_bounds__(256) void k_scan1(const int* __restrict__ deg,
                                               int* __restrict__ bsum, int n) {
    __shared__ int s[256];
    const int tid = threadIdx.x;
    const int base = blockIdx.x * SCAN_TILE + tid * 8;
    int sum = 0;
#pragma unroll
    for (int i = 0; i < 8; ++i) { int idx = base + i; if (idx < n) sum += deg[idx]; }
    s[tid] = sum;
    __syncthreads();
#pragma unroll
    for (int off = 128; off > 0; off >>= 1) {
        if (tid < off) s[tid] += s[tid + off];
        __syncthreads();
    }
    if (tid == 0) bsum[blockIdx.x] = s[0];
}

__global__ __launch_bounds__(256) void k_scan2(const int* __restrict__ bsum,
                                               int* __restrict__ bscan, int nb) {
    __shared__ int s[256];
    const int tid = threadIdx.x;
    s[tid] = (tid < nb) ? bsum[tid] : 0;
    __syncthreads();
#pragma unroll
    for (int off = 1; off < 256; off <<= 1) {
        int v = (tid >= off) ? s[tid - off] : 0;
        __syncthreads();
        s[tid] += v;
        __syncthreads();
    }
    if (tid < nb) bscan[tid] = (tid == 0) ? 0 : s[tid - 1];
}

__global__ __launch_bounds__(256) void k_scan3(const int* __restrict__ deg,
                                               const int* __restrict__ bscan,
                                               int* __restrict__ row_ptr,
                                               int* __restrict__ row_fill,
                                               int n, int E) {
    __shared__ int s[256];
    const int tid = threadIdx.x;
    const int base = blockIdx.x * SCAN_TILE + tid * 8;
    int v[8];
#pragma unroll
    for (int i = 0; i < 8; ++i) { int idx = base + i; v[i] = (idx < n) ? deg[idx] : 0; }
    int sum = 0;
#pragma unroll
    for (int i = 0; i < 8; ++i) sum += v[i];
    s[tid] = sum;
    __syncthreads();
#pragma unroll
    for (int off = 1; off < 256; off <<= 1) {
        int t = (tid >= off) ? s[tid - off] : 0;
        __syncthreads();
        s[tid] += t;
        __syncthreads();
    }
    int run = bscan[blockIdx.x] + ((tid == 0) ? 0 : s[tid - 1]);
#pragma unroll
    for (int i = 0; i < 8; ++i) {
        int idx = base + i;
        if (idx < n) {
            row_ptr[idx]  = run;
            row_fill[idx] = run;
            run += v[i];
        }
    }
    if (blockIdx.x == 0 && tid == 0) row_ptr[n] = E;
}

__global__ void k_scatter(const int* __restrict__ rows, const int* __restrict__ cols,
                          const float* __restrict__ ew, int* __restrict__ row_fill,
                          int2* __restrict__ ep, int E) {
    int i = blockIdx.x * blockDim.x + threadIdx.x;
    if (i < E) {
        int r = rows[i];
        int p = atomicAdd(&row_fill[r], 1);
        ep[p] = make_int2(cols[i], __float_as_int(ew[i]));
    }
}

// ---------------------------------------------------------------------------
// Merged weight transpose + bf16 convert for W1 and W2 (one launch).
// Block 0 additionally zeroes the bucket-count array (kills a memset dispatch).
// ---------------------------------------------------------------------------
__global__ void k_wcvt2(const float* __restrict__ W1, ushort_t* __restrict__ Wt1,
                        const float* __restrict__ W2, ushort_t* __restrict__ Wt2,
                        int* __restrict__ bcnt) {
    if (blockIdx.x == 0) {
        bcnt[threadIdx.x] = 0;
        bcnt[threadIdx.x + 256] = 0;
    }
    int i = blockIdx.x * blockDim.x + threadIdx.x;
    if (i < IN_DIM * HID_DIM) {
        int k = i / HID_DIM, c = i % HID_DIM;
        Wt1[(size_t)c * IN_DIM + k] = f2bf(W1[i]);
    } else {
        int j = i - IN_DIM * HID_DIM;
        if (j < HID_DIM * OUT_DIM) {
            int k = j / OUT_DIM, c = j % OUT_DIM;
            Wt2[(size_t)c * HID_DIM + k] = f2bf(W2[j]);
        }
    }
}

// ---------------------------------------------------------------------------
// MFMA bf16 GEMM: C[n x DC] = A[n x DK] @ W[DK x DC], fp32 accumulate.
// Double-buffered LDS: one barrier per K-step; global loads for step k+1 are
// issued before the MFMA block of step k so HBM latency hides under compute.
// OUT_FP8: store e4m3 (sup1, gathered by spmm1); else store bf16.
// ---------------------------------------------------------------------------
template <int DK, int DC, bool A_BF16, bool OUT_FP8>
__global__ __launch_bounds__(256) void k_gemm_mfma(const void* __restrict__ Av,
                                                   const ushort_t* __restrict__ Wt,
                                                   void* __restrict__ Cv, int n) {
    constexpr int BR = 64, BK = 32, NT = DC / 16, SA = 40;
    __shared__ __align__(16) ushort_t As[2][BR * SA];
    __shared__ __align__(16) ushort_t Ws[2][DC * SA];

    const int tid  = threadIdx.x;
    const int wv   = tid >> 6;
    const int lane = tid & 63;
    const int m    = lane & 15;
    const int quad = lane >> 4;
    const int row0 = blockIdx.x * BR;

    floatx4 acc[NT];
#pragma unroll
    for (int t = 0; t < NT; ++t) acc[t] = (floatx4){0.f, 0.f, 0.f, 0.f};

    const int ar = tid >> 2;
    const int ak = (tid & 3) * 8;
    int arr = row0 + ar; if (arr >= n) arr = n - 1;
    const int wc = (DC == 128) ? (tid >> 1) : (tid >> 2);
    const int wk = (DC == 128) ? ((tid & 1) * 16) : ((tid & 3) * 8);

    float4 af0, af1;   // A staging (fp32 input path)
    ushort8 ab;        // A staging (bf16 input path)
    ushort8 wr0, wr1;  // W staging

#define GLOAD(K0) {                                                                          \
        if constexpr (A_BF16) {                                                              \
            ab = *reinterpret_cast<const ushort8*>(                                          \
                     (const ushort_t*)Av + (size_t)arr * DK + (K0) + ak);                    \
        } else {                                                                             \
            const float* Ab = (const float*)Av + (size_t)arr * DK + (K0) + ak;               \
            af0 = *reinterpret_cast<const float4*>(Ab);                                      \
            af1 = *reinterpret_cast<const float4*>(Ab + 4);                                  \
        }                                                                                    \
        wr0 = *reinterpret_cast<const ushort8*>(&Wt[(size_t)wc * DK + (K0) + wk]);           \
        if constexpr (DC == 128)                                                             \
            wr1 = *reinterpret_cast<const ushort8*>(&Wt[(size_t)wc * DK + (K0) + wk + 8]);   \
    }
#define LSTORE(BUF) {                                                                        \
        ushort8 ap;                                                                          \
        if constexpr (A_BF16) ap = ab;                                                       \
        else ap = (ushort8){ f2bf(af0.x), f2bf(af0.y), f2bf(af0.z), f2bf(af0.w),             \
                             f2bf(af1.x), f2bf(af1.y), f2bf(af1.z), f2bf(af1.w) };           \
        *reinterpret_cast<ushort8*>(&As[BUF][ar * SA + ak]) = ap;                            \
        *reinterpret_cast<ushort8*>(&Ws[BUF][wc * SA + wk]) = wr0;                           \
        if constexpr (DC == 128)                                                             \
            *reinterpret_cast<ushort8*>(&Ws[BUF][wc * SA + wk + 8]) = wr1;                   \
    }

    GLOAD(0);
    LSTORE(0);
    __syncthreads();
    int cur = 0;
#pragma unroll
    for (int k0 = 0; k0 < DK; k0 += BK) {
        const int nxt = k0 + BK;
        if (nxt < DK) GLOAD(nxt);
        bf16x8 a = *reinterpret_cast<bf16x8*>(&As[cur][(wv * 16 + m) * SA + quad * 8]);
#pragma unroll
        for (int t = 0; t < NT; ++t) {
            bf16x8 bfr = *reinterpret_cast<bf16x8*>(&Ws[cur][(t * 16 + m) * SA + quad * 8]);
            acc[t] = __builtin_amdgcn_mfma_f32_16x16x32_bf16(a, bfr, acc[t], 0, 0, 0);
        }
        if (nxt < DK) {
            LSTORE(cur ^ 1);   // write the buffer nobody reads this step
            __syncthreads();   // single barrier per K-step
            cur ^= 1;
        }
    }
#undef GLOAD
#undef LSTORE

#pragma unroll
    for (int t = 0; t < NT; ++t) {
#pragma unroll
        for (int i = 0; i < 4; ++i) {
            int r = row0 + wv * 16 + quad * 4 + i;
            if (r < n) {
                if constexpr (OUT_FP8)
                    ((unsigned char*)Cv)[(size_t)r * DC + t * 16 + m] = f2fp8(acc[t][i]);
                else
                    ((ushort_t*)Cv)[(size_t)r * DC + t * 16 + m] = f2bf(acc[t][i]);
            }
        }
    }
}

// ---------------------------------------------------------------------------
// CSR SpMM, one wave per row. Half-wave edge pairing: lanes 0-31 process edge
// A, lanes 32-63 edge B of each pair; every lane gathers a dword (4 fp8 dims
// or 2 bf16 dims), so one gather instruction covers TWO edges. Segments are
// padded to 8 records (w=0 dummies) -> aligned dwordx4 ep loads, no tails.
// Partial sums combined with shfl_xor(32) in the epilogue.
// ---------------------------------------------------------------------------

// Layer 1: sup = fp8 e4m3 [n x 128], out h = bf16 [n x 128], bias + relu.
__global__ __launch_bounds__(256) void k_spmm1(const int2* __restrict__ rseg,
                                               const unsigned* __restrict__ ep4,
                                               const unsigned char* __restrict__ sup,
                                               const float* __restrict__ bias,
                                               ushort_t* __restrict__ h, int n) {
    const int w    = (blockIdx.x * 256 + threadIdx.x) >> 6;
    const int lane = threadIdx.x & 63;
    const int half = lane >> 5;
    const int hl   = lane & 31;
    if (w >= n) return;
    const int2 seg = rseg[w];

    float a0 = 0.f, a1 = 0.f, a2 = 0.f, a3 = 0.f;
    const int hoff = hl << 2;
    auto pair = [&](unsigned ra, unsigned rb) {
        unsigned r = half ? rb : ra;
        float ww = __half2float(__ushort_as_half((ushort_t)(r >> 16)));
        unsigned v = *reinterpret_cast<const unsigned*>(
            sup + (((size_t)(r & 0xFFFFu)) << 7) + hoff);
        a0 = fmaf(ww, fp82f((unsigned char)(v & 255u)), a0);
        a1 = fmaf(ww, fp82f((unsigned char)((v >> 8) & 255u)), a1);
        a2 = fmaf(ww, fp82f((unsigned char)((v >> 16) & 255u)), a2);
        a3 = fmaf(ww, fp82f((unsigned char)(v >> 24)), a3);
    };
    for (int i = seg.x; i < seg.y; i += 8) {
        uint4 qa = *reinterpret_cast<const uint4*>(ep4 + i);
        uint4 qb = *reinterpret_cast<const uint4*>(ep4 + i + 4);
        pair(qa.x, qa.y); pair(qa.z, qa.w);
        pair(qb.x, qb.y); pair(qb.z, qb.w);
    }
    a0 += __shfl_xor(a0, 32); a1 += __shfl_xor(a1, 32);
    a2 += __shfl_xor(a2, 32); a3 += __shfl_xor(a3, 32);
    if (half == 0) {
        const int d = hl << 2;
        a0 = fmaxf(a0 + bias[d], 0.f);
        a1 = fmaxf(a1 + bias[d + 1], 0.f);
        a2 = fmaxf(a2 + bias[d + 2], 0.f);
        a3 = fmaxf(a3 + bias[d + 3], 0.f);
        unsigned p0 = (unsigned)f2bf(a0) | ((unsigned)f2bf(a1) << 16);
        unsigned p1 = (unsigned)f2bf(a2) | ((unsigned)f2bf(a3) << 16);
        *reinterpret_cast<uint2*>(h + (size_t)w * HID_DIM + d) = make_uint2(p0, p1);
    }
}

// Layer 2: sup = bf16 [n x 64], out = fp32 [n x 64], bias, no relu.
__global__ __launch_bounds__(256) void k_spmm2(const int2* __restrict__ rseg,
                                               const unsigned* __restrict__ ep4,
                                               const ushort_t* __restrict__ sup,
                                               const float* __restrict__ bias,
                                               float* __restrict__ out, int n) {
    const int w    = (blockIdx.x * 256 + threadIdx.x) >> 6;
    const int lane = threadIdx.x & 63;
    const int half = lane >> 5;
    const int hl   = lane & 31;
    if (w >= n) return;
    const int2 seg = rseg[w];

    float ax = 0.f, ay = 0.f;
    const unsigned char* supb = (const unsigned char*)sup;
    const int hoff = hl << 2;
    auto pair = [&](unsigned ra, unsigned rb) {
        unsigned r = half ? rb : ra;
        float ww = __half2float(__ushort_as_half((ushort_t)(r >> 16)));
        unsigned v = *reinterpret_cast<const unsigned*>(
            supb + (((size_t)(r & 0xFFFFu)) << 7) + hoff);
        ax = fmaf(ww, __uint_as_float(v << 16), ax);
        ay = fmaf(ww, __uint_as_float(v & 0xFFFF0000u), ay);
    };
    for (int i = seg.x; i < seg.y; i += 8) {
        uint4 qa = *reinterpret_cast<const uint4*>(ep4 + i);
        uint4 qb = *reinterpret_cast<const uint4*>(ep4 + i + 4);
        pair(qa.x, qa.y); pair(qa.z, qa.w);
        pair(qb.x, qb.y); pair(qb.z, qb.w);
    }
    ax += __shfl_xor(ax, 32); ay += __shfl_xor(ay, 32);
    if (half == 0) {
        const int d = hl << 1;
        *reinterpret_cast<float2*>(out + (size_t)w * OUT_DIM + d) =
            make_float2(ax + bias[d], ay + bias[d + 1]);
    }
}

// Legacy SpMM (8-byte int2 records, fp32 weights) — fallback path only.
template <int D, bool RELU, bool OUT_BF16, bool SUP_FP8>
__global__ __launch_bounds__(256) void k_spmm_legacy(const int* __restrict__ rp,
                                                     const int2* __restrict__ ep,
                                                     const void* __restrict__ supv,
                                                     const float* __restrict__ bias,
                                                     void* __restrict__ outv, int n) {
    const int w    = (blockIdx.x * 256 + threadIdx.x) >> 6;
    const int lane = threadIdx.x & 63;
    if (w >= n) return;
    const int s = rp[w], e = rp[w + 1];

    if constexpr (D == 128) {
        const int d = lane * 2;
        float accx = 0.f, accy = 0.f;
        for (int i = s; i < e; ++i) {
            int2 r = ep[i];
            float ww = __int_as_float(r.y);
            if constexpr (SUP_FP8) {
                const unsigned char* sup = (const unsigned char*)supv;
                unsigned short u = *reinterpret_cast<const unsigned short*>(&sup[(size_t)r.x * D + d]);
                accx = fmaf(ww, fp82f((unsigned char)(u & 255)), accx);
                accy = fmaf(ww, fp82f((unsigned char)(u >> 8)), accy);
            } else {
                const ushort_t* sup = (const ushort_t*)supv;
                unsigned u = *reinterpret_cast<const unsigned*>(&sup[(size_t)r.x * D + d]);
                accx = fmaf(ww, __uint_as_float(u << 16), accx);
                accy = fmaf(ww, __uint_as_float(u & 0xFFFF0000u), accy);
            }
        }
        accx += bias[d]; accy += bias[d + 1];
        if (RELU) { accx = fmaxf(accx, 0.f); accy = fmaxf(accy, 0.f); }
        if constexpr (OUT_BF16) {
            unsigned pk = (unsigned)f2bf(accx) | ((unsigned)f2bf(accy) << 16);
            *reinterpret_cast<unsigned*>((ushort_t*)outv + (size_t)w * D + d) = pk;
        } else {
            *reinterpret_cast<float2*>((float*)outv + (size_t)w * D + d) =
                make_float2(accx, accy);
        }
    } else {
        const int d = lane;
        const ushort_t* sup = (const ushort_t*)supv;
        float acc = 0.f;
        for (int i = s; i < e; ++i) {
            int2 r = ep[i];
            acc = fmaf(__int_as_float(r.y), bf2f(sup[(size_t)r.x * D + d]), acc);
        }
        acc += bias[d];
        if (RELU) acc = fmaxf(acc, 0.f);
        if constexpr (OUT_BF16)
            ((ushort_t*)outv)[(size_t)w * D + d] = f2bf(acc);
        else
            ((float*)outv)[(size_t)w * D + d] = acc;
    }
}

// ---------------------------------------------------------------------------

extern "C" void kernel_launch(void* const* d_in, const int* in_sizes, int n_in,
                              void* d_out, int out_size, void* d_ws, size_t ws_size,
                              hipStream_t stream) {
    const float* x  = (const float*)d_in[0];
    const int*   ei = (const int*)d_in[1];
    const float* ew = (const float*)d_in[2];
    const float* W1 = (const float*)d_in[3];
    const float* b1 = (const float*)d_in[4];
    const float* W2 = (const float*)d_in[5];
    const float* b2 = (const float*)d_in[6];
    float* out = (float*)d_out;

    const int n = in_sizes[0] / IN_DIM;  // 50000
    const int E = in_sizes[2];           // 1600000
    const int* rows = ei;
    const int* cols = ei + E;

    char* ws = (char*)d_ws;
    size_t off = 0;
    auto alloc = [&](size_t bytes) -> void* {
        off = (off + 255) & ~(size_t)255;
        void* p = ws + off;
        off += bytes;
        return p;
    };
    // padded edge capacity: E + per-bucket slack
    const size_t epad = (size_t)E + (size_t)NBMAX * BSLACK;
    unsigned* ep4     = (unsigned*)alloc(epad * sizeof(unsigned));
    int2*     rseg    = (int2*)alloc((size_t)n * sizeof(int2));
    int*      bcnt    = (int*)alloc(NBMAX * sizeof(int));
    int*      bbase   = (int*)alloc((NBMAX + 1) * sizeof(int));
    int*      bfill   = (int*)alloc(NBMAX * sizeof(int));
    ushort_t* Wt1     = (ushort_t*)alloc((size_t)IN_DIM * HID_DIM * sizeof(ushort_t));
    ushort_t* Wt2     = (ushort_t*)alloc((size_t)HID_DIM * OUT_DIM * sizeof(ushort_t));
    // shared region: ept (bin temp, epad*8B) | sup1 (n*128 fp8) | sup2 (n*64 bf16)
    size_t sup1_bytes = (size_t)n * HID_DIM;
    size_t sup2_bytes = (size_t)n * OUT_DIM * sizeof(ushort_t);
    size_t ept_bytes  = epad * sizeof(int2);
    size_t reg = sup1_bytes > ept_bytes ? sup1_bytes : ept_bytes;
    if (sup2_bytes > reg) reg = sup2_bytes;
    unsigned char* sup1 = (unsigned char*)alloc(reg);
    ushort_t* h    = (ushort_t*)alloc((size_t)n * HID_DIM * sizeof(ushort_t));
    ushort_t* sup2 = (ushort_t*)sup1;  // sup1 dead after spmm1
    int2*     ept  = (int2*)sup1;      // bin temp aliases sup1 (dead until gemm1)

    const int nbk = (n + 127) / 128;
    const int gemm_b = (n + 63) / 64;

    // --- weight prep + bcnt zero (one merged launch) ---
    k_wcvt2<<<(IN_DIM * HID_DIM + HID_DIM * OUT_DIM + 255) / 256, 256, 0, stream>>>(
        W1, Wt1, W2, Wt2, bcnt);

    if (n <= 65536) {
        // --- CSR build, bucket-level, 4B padded records ---
        k_bhist<<<(E + BH_TILE - 1) / BH_TILE, 256, 0, stream>>>(rows, bcnt, E);
        k_bscan<<<1, 256, 0, stream>>>(bcnt, bbase, bfill, nbk);
        k_bin<<<(E + BIN_TILE - 1) / BIN_TILE, 256, 0, stream>>>(rows, cols, ew, bfill, ept, E, nbk);
        k_unbin<<<nbk, 256, 0, stream>>>(bbase, bcnt, ept, ep4, rseg, n);

        // --- Layer 1: gemm (fp32->bf16 MFMA, fp8 out) + paired-gather spmm ---
        k_gemm_mfma<IN_DIM, HID_DIM, false, true><<<gemm_b, 256, 0, stream>>>(x, Wt1, sup1, n);
        k_spmm1<<<(n + 3) / 4, 256, 0, stream>>>(rseg, ep4, sup1, b1, h, n);

        // --- Layer 2: gemm (bf16 in, bf16 out) + paired-gather spmm ---
        k_gemm_mfma<HID_DIM, OUT_DIM, true, false><<<gemm_b, 256, 0, stream>>>(h, Wt2, sup2, n);
        k_spmm2<<<(n + 3) / 4, 256, 0, stream>>>(rseg, ep4, sup2, b2, out, n);
    } else {
        // --- fallback: row-level hist -> scan -> direct scatter (8B recs) ---
        int*  row_ptr  = (int*)alloc((size_t)(n + 1) * sizeof(int));
        int*  deg      = (int*)alloc((size_t)n * sizeof(int));
        int*  row_fill = (int*)alloc((size_t)n * sizeof(int));
        int*  bsum     = (int*)alloc(256 * sizeof(int));
        int*  bscn     = (int*)alloc(256 * sizeof(int));
        int2* ep8      = (int2*)alloc((size_t)E * sizeof(int2));
        const int nb = (n + SCAN_TILE - 1) / SCAN_TILE;
        k_zero<<<(n + 255) / 256, 256, 0, stream>>>(deg, n);
        k_hist<<<(E + 255) / 256, 256, 0, stream>>>(rows, deg, E);
        k_scan1<<<nb, 256, 0, stream>>>(deg, bsum, n);
        k_scan2<<<1, 256, 0, stream>>>(bsum, bscn, nb);
        k_scan3<<<nb, 256, 0, stream>>>(deg, bscn, row_ptr, row_fill, n, E);
        k_scatter<<<(E + 255) / 256, 256, 0, stream>>>(rows, cols, ew, row_fill, ep8, E);

        k_gemm_mfma<IN_DIM, HID_DIM, false, true><<<gemm_b, 256, 0, stream>>>(x, Wt1, sup1, n);
        k_spmm_legacy<HID_DIM, true, true, true><<<(n + 3) / 4, 256, 0, stream>>>(row_ptr, ep8, sup1, b1, h, n);
        k_gemm_mfma<HID_DIM, OUT_DIM, true, false><<<gemm_b, 256, 0, stream>>>(h, Wt2, sup2, n);
        k_spmm_legacy<OUT_DIM, false, false, false><<<(n + 3) / 4, 256, 0, stream>>>(row_ptr, ep8, sup2, b2, out, n);
    }
}